// Round 10
// baseline (453.399 us; speedup 1.0000x reference)
//
#include <hip/hip_runtime.h>

#define T_DIM 1024
#define B_DIM 16
#define D_DIM 512
#define K_W   31
#define PAD   15

// ===========================================================================
// ALL numeric ops are f32 with NO fma contraction and numpy-sequential
// reduction order, to bit-match the harness's strict-sequential f32 np ref.
// Rounds 5-9 PASSED with absmax 0.0 — do NOT change rounding/order/precision:
// f64 accuracy FLIPS a borderline spike (rounds 1-4, absmax 0.998046875).
// ===========================================================================

// ---------------------------------------------------------------------------
// K1: pointwise GEMM, f32, strict d-ascending accumulation, no FMA.
// R10: BK=16 double-buffered (LDS 35328 B) -> 4 blocks/CU, 4 waves/SIMD
// (R9 was 2: VALU pipe ~85% occupied, barrier edges uncovered). One barrier
// per k0-step; global prefetch issued before compute; staging writes go to
// buf^1. Strides S_E=146 / S_T=130 (4*S = 8 mod 32 -> 2-way worst = free,
// BK-independent). Arithmetic order identical (strict ascending d).
// ---------------------------------------------------------------------------
#define S_E 146
#define S_T 130
__global__ __launch_bounds__(256, 4)
void pw_gemm(const float* __restrict__ inp, const float* __restrict__ w_pw,
             const float* __restrict__ b_pw, float* __restrict__ Yw,
             int tau0, int tau1, int NTW)
{
#pragma clang fp contract(off)
    __shared__ float Es[2][16 * S_E];   // [buf][k][skew(e_local)] 128 e
    __shared__ float Ts[2][16 * S_T];   // [buf][k][tau_local]     128 tau

    const int tid = threadIdx.x;
    const int e0  = blockIdx.x * 128;
    int tg0 = tau0 + blockIdx.y * 128;           // tau tile base
    if (tg0 + 128 > tau1) {                      // shift last tile; overlap
        int s = tau1 - 128;                      // writes identical values
        tg0 = (s > tau0) ? s : tau0;
    }
    const int b  = blockIdx.z;
    const int rt = tid >> 4;                     // tau-sub 0..15 (8 tau each)
    const int ce = tid & 15;                     // e-sub   0..15 (8 e each)
    const int eoff = ce * 8 + ((ce >> 2) << 2);  // skewed read base

    float acc[8][8];
#pragma unroll
    for (int i = 0; i < 8; ++i)
#pragma unroll
        for (int j = 0; j < 8; ++j) acc[i][j] = 0.0f;

    float4 av[2], xv[2];

    // ---- prologue: load k-block 0 (16 k) and stage into buf 0
#pragma unroll
    for (int i = 0; i < 2; ++i) {
        int cid = tid + 256 * i;                 // 0..511
        int row = cid >> 2;                      // 0..127
        int kq  = cid & 3;                       // 16B chunk within 16 floats
        int trow = tg0 + row;
        if (trow > T_DIM - 1) trow = T_DIM - 1;
        av[i] = *(const float4*)&w_pw[(size_t)(e0 + row) * D_DIM + kq * 4];
        xv[i] = *(const float4*)&inp[(size_t)trow * (B_DIM * D_DIM)
                                     + (size_t)b * D_DIM + kq * 4];
    }
#pragma unroll
    for (int i = 0; i < 2; ++i) {
        int cid = tid + 256 * i;
        int row = cid >> 2;
        int kq  = cid & 3;
        int srow = row + ((row >> 5) << 2);      // skew(e)
        Es[0][(kq * 4 + 0) * S_E + srow] = av[i].x;
        Es[0][(kq * 4 + 1) * S_E + srow] = av[i].y;
        Es[0][(kq * 4 + 2) * S_E + srow] = av[i].z;
        Es[0][(kq * 4 + 3) * S_E + srow] = av[i].w;
        Ts[0][(kq * 4 + 0) * S_T + row] = xv[i].x;
        Ts[0][(kq * 4 + 1) * S_T + row] = xv[i].y;
        Ts[0][(kq * 4 + 2) * S_T + row] = xv[i].z;
        Ts[0][(kq * 4 + 3) * S_T + row] = xv[i].w;
    }

    int cur = 0;
    for (int k0 = 0; k0 < D_DIM; k0 += 16) {     // strict ascending d blocks
        __syncthreads();                         // buf[cur] ready for all

        const bool has_next = (k0 + 16 < D_DIM);
        if (has_next) {                          // issue next block's globals
#pragma unroll
            for (int i = 0; i < 2; ++i) {
                int cid = tid + 256 * i;
                int row = cid >> 2;
                int kq  = cid & 3;
                int trow = tg0 + row;
                if (trow > T_DIM - 1) trow = T_DIM - 1;
                av[i] = *(const float4*)&w_pw[(size_t)(e0 + row) * D_DIM
                                              + k0 + 16 + kq * 4];
                xv[i] = *(const float4*)&inp[(size_t)trow * (B_DIM * D_DIM)
                                             + (size_t)b * D_DIM + k0 + 16 + kq * 4];
            }
        }

#pragma unroll
        for (int kk = 0; kk < 16; ++kk) {        // strict ascending d
            float4 tf0 = *(const float4*)&Ts[cur][kk * S_T + rt * 8];
            float4 tf1 = *(const float4*)&Ts[cur][kk * S_T + rt * 8 + 4];
            float4 ef0 = *(const float4*)&Es[cur][kk * S_E + eoff];
            float4 ef1 = *(const float4*)&Es[cur][kk * S_E + eoff + 4];
            float a[8] = {tf0.x, tf0.y, tf0.z, tf0.w, tf1.x, tf1.y, tf1.z, tf1.w};
            float x[8] = {ef0.x, ef0.y, ef0.z, ef0.w, ef1.x, ef1.y, ef1.z, ef1.w};
#pragma unroll
            for (int i = 0; i < 8; ++i)
#pragma unroll
                for (int j = 0; j < 8; ++j)
                    acc[i][j] = __fadd_rn(acc[i][j], __fmul_rn(a[i], x[j]));
        }

        if (has_next) {                          // stage into the other buffer
            const int nxt = cur ^ 1;
#pragma unroll
            for (int i = 0; i < 2; ++i) {
                int cid = tid + 256 * i;
                int row = cid >> 2;
                int kq  = cid & 3;
                int srow = row + ((row >> 5) << 2);
                Es[nxt][(kq * 4 + 0) * S_E + srow] = av[i].x;
                Es[nxt][(kq * 4 + 1) * S_E + srow] = av[i].y;
                Es[nxt][(kq * 4 + 2) * S_E + srow] = av[i].z;
                Es[nxt][(kq * 4 + 3) * S_E + srow] = av[i].w;
                Ts[nxt][(kq * 4 + 0) * S_T + row] = xv[i].x;
                Ts[nxt][(kq * 4 + 1) * S_T + row] = xv[i].y;
                Ts[nxt][(kq * 4 + 2) * S_T + row] = xv[i].z;
                Ts[nxt][(kq * 4 + 3) * S_T + row] = xv[i].w;
            }
            cur = nxt;
        }
    }

    float bias[8];
#pragma unroll
    for (int j = 0; j < 8; ++j) bias[j] = b_pw[e0 + ce * 8 + j];

#pragma unroll
    for (int i = 0; i < 8; ++i) {
        int tau = tg0 + rt * 8 + i;
        if (tau < tau1) {
            float* yrow = Yw + ((size_t)b * NTW + (tau - tau0)) * D_DIM + e0 + ce * 8;
#pragma unroll
            for (int j = 0; j < 8; ++j)
                yrow[j] = __fadd_rn(acc[i][j], bias[j]);
        }
    }
}

// ---------------------------------------------------------------------------
// K2: depthwise conv, f32, strict k-ascending, no FMA, zero padding.
// (byte-identical to rounds 5-9 — proven bit-exact)
// ---------------------------------------------------------------------------
__global__ __launch_bounds__(512, 1)
void dw_conv(const float* __restrict__ Yw, const float* __restrict__ w_dw,
             float* __restrict__ Zw, int t0, int tau0, int NTW)
{
#pragma clang fp contract(off)
    const int d  = threadIdx.x;              // 0..511
    const int tb = blockIdx.x * 8;           // t offset within pass
    const int b  = blockIdx.y;

    float wd[K_W];
#pragma unroll
    for (int k = 0; k < K_W; ++k) wd[k] = w_dw[d * K_W + k];

    const float* ybase = Yw + (size_t)b * NTW * D_DIM + d;

    float yw[38];
#pragma unroll
    for (int i = 0; i < 38; ++i) {
        int tau = t0 + tb - PAD + i;
        yw[i] = (tau >= 0 && tau < T_DIM)
              ? ybase[(size_t)(tau - tau0) * D_DIM] : 0.0f;
    }

#pragma unroll
    for (int j = 0; j < 8; ++j) {
        float z = 0.0f;
#pragma unroll
        for (int k = 0; k < K_W; ++k)        // strict ascending k
            z = __fadd_rn(z, __fmul_rn(wd[k], yw[j + k]));
        Zw[((size_t)(tb + j) * B_DIM + b) * D_DIM + d] = z;
    }
}

// ---------------------------------------------------------------------------
// K3: EXACT sequential LIF scan, f32, numpy op-for-op. z-loads only; packed
// u32 spike bitmasks; 32-step double buffer. R10 micro-opt: reset via
// cndmask (v = sp ? 0 : v). Sign-of-zero note: v*(1-s) could produce -0
// where select gives +0, but ±0 are indistinguishable through 0.5*v+z and
// the >= compare for every continuation, so spikes (the only observable)
// are bit-identical.
// ---------------------------------------------------------------------------
__global__ __launch_bounds__(64, 1)
void lif_scan(const float* __restrict__ Zw, unsigned* __restrict__ sw,
              float* __restrict__ vst, int L, int first)
{
#pragma clang fp contract(off)
    const int lane = threadIdx.x;
    const int b    = blockIdx.x >> 3;                 // 0..15
    const int d    = ((blockIdx.x & 7) << 6) + lane;  // 0..511
    const int gi   = b * D_DIM + d;

    float v = first ? 0.0f : vst[gi];

    const float* zp = Zw + (size_t)b * D_DIM + d;
    unsigned*    wp = sw + gi;                        // + (t>>5)*B*D
    const size_t st = (size_t)B_DIM * D_DIM;
    const int Lm1 = L - 1;

    float zA[32], zB[32];
#pragma unroll
    for (int j = 0; j < 32; ++j) zA[j] = zp[(size_t)j * st];   // L >= 64

    for (int tb = 0; tb < L; tb += 64) {     // L is a multiple of 64
#pragma unroll
        for (int j = 0; j < 32; ++j) {       // issue steps tb+32..tb+63
            int t = tb + 32 + j; t = (t > Lm1) ? Lm1 : t;
            zB[j] = zp[(size_t)t * st];
        }
        unsigned m = 0;
#pragma unroll
        for (int j = 0; j < 32; ++j) {       // consume steps tb..tb+31
            v = __fadd_rn(__fmul_rn(v, 0.5f), zA[j]);
            const bool sp = (v >= 1.0f);
            m |= (sp ? (1u << j) : 0u);
            v = sp ? 0.0f : v;               // cndmask; ±0-equivalent to v*(1-s)
        }
        wp[(size_t)(tb >> 5) * st] = m;
#pragma unroll
        for (int j = 0; j < 32; ++j) {       // issue steps tb+64..tb+95
            int t = tb + 64 + j; t = (t > Lm1) ? Lm1 : t;
            zA[j] = zp[(size_t)t * st];
        }
        m = 0;
#pragma unroll
        for (int j = 0; j < 32; ++j) {       // consume steps tb+32..tb+63
            v = __fadd_rn(__fmul_rn(v, 0.5f), zB[j]);
            const bool sp = (v >= 1.0f);
            m |= (sp ? (1u << j) : 0u);
            v = sp ? 0.0f : v;
        }
        wp[(size_t)((tb >> 5) + 1) * st] = m;
    }
    vst[gi] = v;
}

// ---------------------------------------------------------------------------
// K4: out[t,b,d] = fl(s + inp[t,b,d]), s = spike bit. (identical to round 7)
// ---------------------------------------------------------------------------
__global__ __launch_bounds__(256, 4)
void spike_add(const unsigned* __restrict__ sw, const float* __restrict__ inp,
               float* __restrict__ out, int t0, int L)
{
#pragma clang fp contract(off)
    const size_t n4 = (size_t)L * B_DIM * D_DIM / 4;
    const float4* ip = (const float4*)(inp + (size_t)t0 * B_DIM * D_DIM);
    float4*       op = (float4*)(out + (size_t)t0 * B_DIM * D_DIM);
    const size_t stride = (size_t)gridDim.x * blockDim.x;

    for (size_t i = (size_t)blockIdx.x * blockDim.x + threadIdx.x;
         i < n4; i += stride) {
        const size_t e    = i * 4;           // element index within pass
        const size_t trel = e >> 13;         // / (B*D = 8192)
        const size_t r    = e & 8191;
        const uint4 w = *(const uint4*)(sw + ((trel >> 5) << 13) + r);
        const unsigned sh = (unsigned)trel & 31u;
        const float4 x = ip[i];
        float4 o;
        o.x = __fadd_rn((float)((w.x >> sh) & 1u), x.x);
        o.y = __fadd_rn((float)((w.y >> sh) & 1u), x.y);
        o.z = __fadd_rn((float)((w.z >> sh) & 1u), x.z);
        o.w = __fadd_rn((float)((w.w >> sh) & 1u), x.w);
        op[i] = o;
    }
}

// ---------------------------------------------------------------------------
// Pass-windowed driver. Spike words overlay the (dead-after-dw_conv) Yw
// region — no extra ws needed. L from ws_size (launch-time constant; R9
// rocprof confirmed L=1024 single-pass on this harness).
// ---------------------------------------------------------------------------
extern "C" void kernel_launch(void* const* d_in, const int* in_sizes, int n_in,
                              void* d_out, int out_size, void* d_ws, size_t ws_size,
                              hipStream_t stream)
{
    const float* inp  = (const float*)d_in[0];   // (T,B,D)
    const float* w_pw = (const float*)d_in[1];   // (D,D)
    const float* b_pw = (const float*)d_in[2];   // (D)
    const float* w_dw = (const float*)d_in[3];   // (D,K)
    float* out = (float*)d_out;

    auto need = [](int L) -> size_t {
        int ntw = (L + 30 > T_DIM) ? T_DIM : (L + 30);
        return ((size_t)ntw + (size_t)L + 1) * (B_DIM * D_DIM * sizeof(float));
    };
    int L = 64;
    if      (ws_size >= need(1024)) L = 1024;
    else if (ws_size >= need(512))  L = 512;
    else if (ws_size >= need(256))  L = 256;
    else if (ws_size >= need(128))  L = 128;

    const int NTWmax = (L + 30 > T_DIM) ? T_DIM : (L + 30);
    float* Yw  = (float*)d_ws;
    float* Zw  = Yw + (size_t)NTWmax * B_DIM * D_DIM;
    float* vst = Zw + (size_t)L * B_DIM * D_DIM;
    unsigned* sw = (unsigned*)Yw;                // overlay: Yw dead after dw_conv

    const int P = T_DIM / L;
    for (int p = 0; p < P; ++p) {
        const int t0   = p * L;
        const int t1   = t0 + L;
        const int tau0 = (t0 - PAD > 0) ? (t0 - PAD) : 0;
        const int tau1 = (t1 + PAD < T_DIM) ? (t1 + PAD) : T_DIM;
        const int NTW  = tau1 - tau0;

        dim3 g1(D_DIM / 128, (NTW + 127) / 128, B_DIM);
        pw_gemm<<<g1, 256, 0, stream>>>(inp, w_pw, b_pw, Yw, tau0, tau1, NTW);

        dim3 g2(L / 8, B_DIM);
        dw_conv<<<g2, 512, 0, stream>>>(Yw, w_dw, Zw, t0, tau0, NTW);

        lif_scan<<<128, 64, 0, stream>>>(Zw, sw, vst, L, p == 0);

        spike_add<<<2048, 256, 0, stream>>>(sw, inp, out, t0, L);
    }
}

// Round 11
// 156.569 us; speedup vs baseline: 2.8958x; 2.8958x over previous
//
#include <hip/hip_runtime.h>

#define T_DIM 1024
#define B_DIM 16
#define D_DIM 512
#define K_W   31
#define PAD   15
#define ST    (B_DIM * D_DIM)

// ===========================================================================
// ALL numeric ops are f32 with NO fma contraction and numpy-sequential
// reduction order, to bit-match the harness's strict-sequential f32 np ref.
// Rounds 5-10 PASSED with absmax 0.0 — do NOT change rounding/order/precision:
// f64 accuracy FLIPS a borderline spike (rounds 1-4, absmax 0.998046875).
// R10 lesson: BK=16 halves cache-line utilization of the staged tiles and
// thrashes L2 (FETCH 67->529 MB, 3.4x slower). Keep BK=32, 2 blocks/CU.
// ===========================================================================

// ---------------------------------------------------------------------------
// K1: pointwise GEMM — byte-identical to ROUND 9 (128 us, 85% of the no-FMA
// VALU roofline): 128e x 128tau tile, BK=32 double-buffered LDS, one barrier
// per k0-step, prefetch before compute, S_E=146/S_T=130 (4*S = 8 mod 32 ->
// staging-write conflicts 2-way worst = free).
// ---------------------------------------------------------------------------
#define S_E 146
#define S_T 130
__global__ __launch_bounds__(256, 2)
void pw_gemm(const float* __restrict__ inp, const float* __restrict__ w_pw,
             const float* __restrict__ b_pw, float* __restrict__ Yw,
             int tau0, int tau1, int NTW)
{
#pragma clang fp contract(off)
    __shared__ float Es[2][32 * S_E];   // [buf][k][skew(e_local)] 128 e
    __shared__ float Ts[2][32 * S_T];   // [buf][k][tau_local]     128 tau

    const int tid = threadIdx.x;
    const int e0  = blockIdx.x * 128;
    int tg0 = tau0 + blockIdx.y * 128;           // tau tile base
    if (tg0 + 128 > tau1) {                      // shift last tile; overlap
        int s = tau1 - 128;                      // writes identical values
        tg0 = (s > tau0) ? s : tau0;
    }
    const int b  = blockIdx.z;
    const int rt = tid >> 4;                     // tau-sub 0..15 (8 tau each)
    const int ce = tid & 15;                     // e-sub   0..15 (8 e each)
    const int eoff = ce * 8 + ((ce >> 2) << 2);  // skewed read base

    float acc[8][8];
#pragma unroll
    for (int i = 0; i < 8; ++i)
#pragma unroll
        for (int j = 0; j < 8; ++j) acc[i][j] = 0.0f;

    float4 av[4], xv[4];

    // ---- prologue: load k0=0 tile and stage into buf 0
#pragma unroll
    for (int i = 0; i < 4; ++i) {
        int cid = tid + 256 * i;
        int row = cid >> 3;
        int kq  = cid & 7;
        int trow = tg0 + row;
        if (trow > T_DIM - 1) trow = T_DIM - 1;
        av[i] = *(const float4*)&w_pw[(size_t)(e0 + row) * D_DIM + kq * 4];
        xv[i] = *(const float4*)&inp[(size_t)trow * (B_DIM * D_DIM)
                                     + (size_t)b * D_DIM + kq * 4];
    }
#pragma unroll
    for (int i = 0; i < 4; ++i) {
        int cid = tid + 256 * i;
        int row = cid >> 3;
        int kq  = cid & 7;
        int srow = row + ((row >> 5) << 2);      // skew(e)
        Es[0][(kq * 4 + 0) * S_E + srow] = av[i].x;
        Es[0][(kq * 4 + 1) * S_E + srow] = av[i].y;
        Es[0][(kq * 4 + 2) * S_E + srow] = av[i].z;
        Es[0][(kq * 4 + 3) * S_E + srow] = av[i].w;
        Ts[0][(kq * 4 + 0) * S_T + row] = xv[i].x;
        Ts[0][(kq * 4 + 1) * S_T + row] = xv[i].y;
        Ts[0][(kq * 4 + 2) * S_T + row] = xv[i].z;
        Ts[0][(kq * 4 + 3) * S_T + row] = xv[i].w;
    }

    int cur = 0;
    for (int k0 = 0; k0 < D_DIM; k0 += 32) {     // strict ascending d blocks
        __syncthreads();                         // buf[cur] ready for all

        const bool has_next = (k0 + 32 < D_DIM);
        if (has_next) {                          // issue next tile's globals
#pragma unroll
            for (int i = 0; i < 4; ++i) {
                int cid = tid + 256 * i;
                int row = cid >> 3;
                int kq  = cid & 7;
                int trow = tg0 + row;
                if (trow > T_DIM - 1) trow = T_DIM - 1;
                av[i] = *(const float4*)&w_pw[(size_t)(e0 + row) * D_DIM
                                              + k0 + 32 + kq * 4];
                xv[i] = *(const float4*)&inp[(size_t)trow * (B_DIM * D_DIM)
                                             + (size_t)b * D_DIM + k0 + 32 + kq * 4];
            }
        }

#pragma unroll 8
        for (int kk = 0; kk < 32; ++kk) {        // strict ascending d
            float4 tf0 = *(const float4*)&Ts[cur][kk * S_T + rt * 8];
            float4 tf1 = *(const float4*)&Ts[cur][kk * S_T + rt * 8 + 4];
            float4 ef0 = *(const float4*)&Es[cur][kk * S_E + eoff];
            float4 ef1 = *(const float4*)&Es[cur][kk * S_E + eoff + 4];
            float a[8] = {tf0.x, tf0.y, tf0.z, tf0.w, tf1.x, tf1.y, tf1.z, tf1.w};
            float x[8] = {ef0.x, ef0.y, ef0.z, ef0.w, ef1.x, ef1.y, ef1.z, ef1.w};
#pragma unroll
            for (int i = 0; i < 8; ++i)
#pragma unroll
                for (int j = 0; j < 8; ++j)
                    acc[i][j] = __fadd_rn(acc[i][j], __fmul_rn(a[i], x[j]));
        }

        if (has_next) {                          // stage into the other buffer
            const int nxt = cur ^ 1;
#pragma unroll
            for (int i = 0; i < 4; ++i) {
                int cid = tid + 256 * i;
                int row = cid >> 3;
                int kq  = cid & 7;
                int srow = row + ((row >> 5) << 2);
                Es[nxt][(kq * 4 + 0) * S_E + srow] = av[i].x;
                Es[nxt][(kq * 4 + 1) * S_E + srow] = av[i].y;
                Es[nxt][(kq * 4 + 2) * S_E + srow] = av[i].z;
                Es[nxt][(kq * 4 + 3) * S_E + srow] = av[i].w;
                Ts[nxt][(kq * 4 + 0) * S_T + row] = xv[i].x;
                Ts[nxt][(kq * 4 + 1) * S_T + row] = xv[i].y;
                Ts[nxt][(kq * 4 + 2) * S_T + row] = xv[i].z;
                Ts[nxt][(kq * 4 + 3) * S_T + row] = xv[i].w;
            }
            cur = nxt;
        }
    }

    float bias[8];
#pragma unroll
    for (int j = 0; j < 8; ++j) bias[j] = b_pw[e0 + ce * 8 + j];

#pragma unroll
    for (int i = 0; i < 8; ++i) {
        int tau = tg0 + rt * 8 + i;
        if (tau < tau1) {
            float* yrow = Yw + ((size_t)b * NTW + (tau - tau0)) * D_DIM + e0 + ce * 8;
#pragma unroll
            for (int j = 0; j < 8; ++j)
                yrow[j] = __fadd_rn(acc[i][j], bias[j]);
        }
    }
}

// ---------------------------------------------------------------------------
// K2 (NEW): FUSED depthwise conv + LIF scan, t-chunked with 64-step f32
// warmup. Eliminates Zw (67 MB traffic) and vst; 8x scan parallelism.
//   - chunk c covers t in [cstart, cstart+128); scan starts at
//     ts = max(0, cstart-64) with v = 0. Chunk 0 is EXACT (true v0 = 0).
//   - warmup safety: warm & true trajectories share every f32 op after ts;
//     the first AGREED spike resets both to exactly 0.0f -> bit-exact merge.
//   - conv: strict k-ascending mul/add over the same Y bits as rounds 5-10's
//     dw_conv -> z bitwise identical.
//   - 54-reg sliding window (8-step groups, static indices only) + pf0/pf1
//     3-group-deep prefetch rotation; spikes packed as u32 bitmasks.
// ---------------------------------------------------------------------------
__global__ __launch_bounds__(64, 2)
void dwlif(const float* __restrict__ Yw, const float* __restrict__ w_dw,
           unsigned* __restrict__ sw, int t0p, int tau0, int NTW)
{
#pragma clang fp contract(off)
    const int lane  = threadIdx.x;
    const int d     = blockIdx.x * 64 + lane;    // 0..511
    const int chunk = blockIdx.y;                // chunk within pass
    const int b     = blockIdx.z;                // 0..15

    const int cstart = t0p + 128 * chunk;
    int ts = cstart - 64; if (ts < 0) ts = 0;    // warmup start (chunk0: 0)
    const int ngroups = (cstart == 0) ? 16 : 24; // (cstart+128 - ts) / 8
    const int outg    = ngroups - 16;            // first output group

    float wd[K_W];
#pragma unroll
    for (int k = 0; k < K_W; ++k) wd[k] = w_dw[d * K_W + k];

    const float* __restrict__ ybase = Yw + (size_t)b * NTW * D_DIM + d;
    unsigned* __restrict__ wp = sw + b * D_DIM + d;

    auto YLD = [&](int tau) -> float {
        int idx = tau - tau0;
        idx = idx < 0 ? 0 : idx;
        idx = idx >= NTW ? NTW - 1 : idx;        // clamped addr, always valid
        float ld = ybase[(size_t)idx * D_DIM];
        return (tau >= 0 && tau < T_DIM) ? ld : 0.0f;   // zero-pad select
    };

    // window: yw[i] = y[tg - 15 + i] for current group base tg (i in [0,54))
    float yw[54], pf0[8], pf1[8];
#pragma unroll
    for (int i = 0; i < 54; ++i) yw[i] = YLD(ts - PAD + i);
#pragma unroll
    for (int j = 0; j < 8; ++j) pf0[j] = YLD(ts + 39 + j);

    float v = 0.0f;
    unsigned m = 0;

#define GROUP(G_EXPR, PF_IN, PF_OUT)                                         \
    {                                                                        \
        const int g  = (G_EXPR);                                             \
        const int tg = ts + 8 * g;                                           \
        _Pragma("unroll")                                                    \
        for (int j = 0; j < 8; ++j) PF_OUT[j] = YLD(tg + 47 + j);            \
        const int mbase = (g & 3) * 8;                                       \
        _Pragma("unroll")                                                    \
        for (int s = 0; s < 8; ++s) {                                        \
            float z = 0.0f;                                                  \
            _Pragma("unroll")                                                \
            for (int k = 0; k < K_W; ++k)     /* strict ascending k */       \
                z = __fadd_rn(z, __fmul_rn(wd[k], yw[s + k]));               \
            v = __fadd_rn(__fmul_rn(v, 0.5f), z);                            \
            const bool sp = (v >= 1.0f);                                     \
            m |= sp ? (1u << (mbase + s)) : 0u;                              \
            v = sp ? 0.0f : v;                /* hard reset (detach) */      \
        }                                                                    \
        _Pragma("unroll")                                                    \
        for (int i = 0; i < 46; ++i) yw[i] = yw[i + 8];                      \
        _Pragma("unroll")                                                    \
        for (int j = 0; j < 8; ++j) yw[46 + j] = PF_IN[j];                   \
        if ((g & 3) == 3) {                                                  \
            if (g >= outg)                                                   \
                wp[(size_t)(4 * chunk + ((g >> 2) - (outg >> 2))) * ST] = m; \
            m = 0;                                                           \
        }                                                                    \
    }

    for (int it = 0; it < ngroups; it += 2) {
        GROUP(it,     pf0, pf1);
        GROUP(it + 1, pf1, pf0);
    }
#undef GROUP
}

// ---------------------------------------------------------------------------
// K3: out[t,b,d] = fl(s + inp[t,b,d]), s = spike bit. (identical to R7-R10)
// ---------------------------------------------------------------------------
__global__ __launch_bounds__(256, 4)
void spike_add(const unsigned* __restrict__ sw, const float* __restrict__ inp,
               float* __restrict__ out, int t0, int L)
{
#pragma clang fp contract(off)
    const size_t n4 = (size_t)L * B_DIM * D_DIM / 4;
    const float4* ip = (const float4*)(inp + (size_t)t0 * B_DIM * D_DIM);
    float4*       op = (float4*)(out + (size_t)t0 * B_DIM * D_DIM);
    const size_t stride = (size_t)gridDim.x * blockDim.x;

    for (size_t i = (size_t)blockIdx.x * blockDim.x + threadIdx.x;
         i < n4; i += stride) {
        const size_t e    = i * 4;           // element index within pass
        const size_t trel = e >> 13;         // / (B*D = 8192)
        const size_t r    = e & 8191;
        const uint4 w = *(const uint4*)(sw + ((trel >> 5) << 13) + r);
        const unsigned sh = (unsigned)trel & 31u;
        const float4 x = ip[i];
        float4 o;
        o.x = __fadd_rn((float)((w.x >> sh) & 1u), x.x);
        o.y = __fadd_rn((float)((w.y >> sh) & 1u), x.y);
        o.z = __fadd_rn((float)((w.z >> sh) & 1u), x.z);
        o.w = __fadd_rn((float)((w.w >> sh) & 1u), x.w);
        op[i] = o;
    }
}

// ---------------------------------------------------------------------------
// Driver: 3 kernels per pass. ws = Yw (NTW rows of 32KB) + sw (L*1024 B).
// Zw and vst are GONE (fused kernel + per-chunk warmup). L from ws_size
// (launch-time constant; R9 rocprof confirmed L=1024 single-pass here).
// Pass tau window must reach t0-79 for the first chunk's warmup taps.
// ---------------------------------------------------------------------------
extern "C" void kernel_launch(void* const* d_in, const int* in_sizes, int n_in,
                              void* d_out, int out_size, void* d_ws, size_t ws_size,
                              hipStream_t stream)
{
    const float* inp  = (const float*)d_in[0];   // (T,B,D)
    const float* w_pw = (const float*)d_in[1];   // (D,D)
    const float* b_pw = (const float*)d_in[2];   // (D)
    const float* w_dw = (const float*)d_in[3];   // (D,K)
    float* out = (float*)d_out;

    auto need = [](int L) -> size_t {
        int ntw = (L + 94 > T_DIM) ? T_DIM : (L + 94);
        return (size_t)ntw * (ST * sizeof(float)) + (size_t)L * 1024;
    };
    int L = 128;
    if      (ws_size >= need(1024)) L = 1024;
    else if (ws_size >= need(512))  L = 512;
    else if (ws_size >= need(256))  L = 256;

    const int NTWmax = (L + 94 > T_DIM) ? T_DIM : (L + 94);
    float*    Yw = (float*)d_ws;
    unsigned* sw = (unsigned*)(Yw + (size_t)NTWmax * ST);

    const int P = T_DIM / L;
    for (int p = 0; p < P; ++p) {
        const int t0   = p * L;
        const int t1   = t0 + L;
        const int tau0 = (t0 - 79 > 0) ? (t0 - 79) : 0;      // warmup halo
        const int tau1 = (t1 + PAD < T_DIM) ? (t1 + PAD) : T_DIM;
        const int NTW  = tau1 - tau0;

        dim3 g1(D_DIM / 128, (NTW + 127) / 128, B_DIM);
        pw_gemm<<<g1, 256, 0, stream>>>(inp, w_pw, b_pw, Yw, tau0, tau1, NTW);

        dim3 g2(D_DIM / 64, L / 128, B_DIM);
        dwlif<<<g2, 64, 0, stream>>>(Yw, w_dw, sw, t0, tau0, NTW);

        spike_add<<<2048, 256, 0, stream>>>(sw, inp, out, t0, L);
    }
}

// Round 12
// 152.802 us; speedup vs baseline: 2.9672x; 1.0247x over previous
//
#include <hip/hip_runtime.h>

#define T_DIM 1024
#define B_DIM 16
#define D_DIM 512
#define K_W   31
#define PAD   15
#define ST    (B_DIM * D_DIM)

// ===========================================================================
// ALL numeric ops are f32 with NO fma contraction and numpy-sequential
// reduction order, to bit-match the harness's strict-sequential f32 np ref.
// Rounds 5-11 PASSED with absmax 0.0 — do NOT change rounding/order/precision:
// f64 accuracy FLIPS a borderline spike (rounds 1-4, absmax 0.998046875).
// R10 lesson: BK=16 halves cache-line utilization and thrashes L2. BK=32.
// ===========================================================================

// ---------------------------------------------------------------------------
// K1: pointwise GEMM — byte-identical to ROUND 9 (128 us, 85% of the no-FMA
// VALU roofline): 128e x 128tau tile, BK=32 double-buffered LDS, one barrier
// per k0-step, prefetch before compute, S_E=146/S_T=130 (4*S = 8 mod 32 ->
// staging-write conflicts 2-way worst = free). FROZEN.
// ---------------------------------------------------------------------------
#define S_E 146
#define S_T 130
__global__ __launch_bounds__(256, 2)
void pw_gemm(const float* __restrict__ inp, const float* __restrict__ w_pw,
             const float* __restrict__ b_pw, float* __restrict__ Yw,
             int tau0, int tau1, int NTW)
{
#pragma clang fp contract(off)
    __shared__ float Es[2][32 * S_E];   // [buf][k][skew(e_local)] 128 e
    __shared__ float Ts[2][32 * S_T];   // [buf][k][tau_local]     128 tau

    const int tid = threadIdx.x;
    const int e0  = blockIdx.x * 128;
    int tg0 = tau0 + blockIdx.y * 128;           // tau tile base
    if (tg0 + 128 > tau1) {                      // shift last tile; overlap
        int s = tau1 - 128;                      // writes identical values
        tg0 = (s > tau0) ? s : tau0;
    }
    const int b  = blockIdx.z;
    const int rt = tid >> 4;                     // tau-sub 0..15 (8 tau each)
    const int ce = tid & 15;                     // e-sub   0..15 (8 e each)
    const int eoff = ce * 8 + ((ce >> 2) << 2);  // skewed read base

    float acc[8][8];
#pragma unroll
    for (int i = 0; i < 8; ++i)
#pragma unroll
        for (int j = 0; j < 8; ++j) acc[i][j] = 0.0f;

    float4 av[4], xv[4];

    // ---- prologue: load k0=0 tile and stage into buf 0
#pragma unroll
    for (int i = 0; i < 4; ++i) {
        int cid = tid + 256 * i;
        int row = cid >> 3;
        int kq  = cid & 7;
        int trow = tg0 + row;
        if (trow > T_DIM - 1) trow = T_DIM - 1;
        av[i] = *(const float4*)&w_pw[(size_t)(e0 + row) * D_DIM + kq * 4];
        xv[i] = *(const float4*)&inp[(size_t)trow * (B_DIM * D_DIM)
                                     + (size_t)b * D_DIM + kq * 4];
    }
#pragma unroll
    for (int i = 0; i < 4; ++i) {
        int cid = tid + 256 * i;
        int row = cid >> 3;
        int kq  = cid & 7;
        int srow = row + ((row >> 5) << 2);      // skew(e)
        Es[0][(kq * 4 + 0) * S_E + srow] = av[i].x;
        Es[0][(kq * 4 + 1) * S_E + srow] = av[i].y;
        Es[0][(kq * 4 + 2) * S_E + srow] = av[i].z;
        Es[0][(kq * 4 + 3) * S_E + srow] = av[i].w;
        Ts[0][(kq * 4 + 0) * S_T + row] = xv[i].x;
        Ts[0][(kq * 4 + 1) * S_T + row] = xv[i].y;
        Ts[0][(kq * 4 + 2) * S_T + row] = xv[i].z;
        Ts[0][(kq * 4 + 3) * S_T + row] = xv[i].w;
    }

    int cur = 0;
    for (int k0 = 0; k0 < D_DIM; k0 += 32) {     // strict ascending d blocks
        __syncthreads();                         // buf[cur] ready for all

        const bool has_next = (k0 + 32 < D_DIM);
        if (has_next) {                          // issue next tile's globals
#pragma unroll
            for (int i = 0; i < 4; ++i) {
                int cid = tid + 256 * i;
                int row = cid >> 3;
                int kq  = cid & 7;
                int trow = tg0 + row;
                if (trow > T_DIM - 1) trow = T_DIM - 1;
                av[i] = *(const float4*)&w_pw[(size_t)(e0 + row) * D_DIM
                                              + k0 + 32 + kq * 4];
                xv[i] = *(const float4*)&inp[(size_t)trow * (B_DIM * D_DIM)
                                             + (size_t)b * D_DIM + k0 + 32 + kq * 4];
            }
        }

#pragma unroll 8
        for (int kk = 0; kk < 32; ++kk) {        // strict ascending d
            float4 tf0 = *(const float4*)&Ts[cur][kk * S_T + rt * 8];
            float4 tf1 = *(const float4*)&Ts[cur][kk * S_T + rt * 8 + 4];
            float4 ef0 = *(const float4*)&Es[cur][kk * S_E + eoff];
            float4 ef1 = *(const float4*)&Es[cur][kk * S_E + eoff + 4];
            float a[8] = {tf0.x, tf0.y, tf0.z, tf0.w, tf1.x, tf1.y, tf1.z, tf1.w};
            float x[8] = {ef0.x, ef0.y, ef0.z, ef0.w, ef1.x, ef1.y, ef1.z, ef1.w};
#pragma unroll
            for (int i = 0; i < 8; ++i)
#pragma unroll
                for (int j = 0; j < 8; ++j)
                    acc[i][j] = __fadd_rn(acc[i][j], __fmul_rn(a[i], x[j]));
        }

        if (has_next) {                          // stage into the other buffer
            const int nxt = cur ^ 1;
#pragma unroll
            for (int i = 0; i < 4; ++i) {
                int cid = tid + 256 * i;
                int row = cid >> 3;
                int kq  = cid & 7;
                int srow = row + ((row >> 5) << 2);
                Es[nxt][(kq * 4 + 0) * S_E + srow] = av[i].x;
                Es[nxt][(kq * 4 + 1) * S_E + srow] = av[i].y;
                Es[nxt][(kq * 4 + 2) * S_E + srow] = av[i].z;
                Es[nxt][(kq * 4 + 3) * S_E + srow] = av[i].w;
                Ts[nxt][(kq * 4 + 0) * S_T + row] = xv[i].x;
                Ts[nxt][(kq * 4 + 1) * S_T + row] = xv[i].y;
                Ts[nxt][(kq * 4 + 2) * S_T + row] = xv[i].z;
                Ts[nxt][(kq * 4 + 3) * S_T + row] = xv[i].w;
            }
            cur = nxt;
        }
    }

    float bias[8];
#pragma unroll
    for (int j = 0; j < 8; ++j) bias[j] = b_pw[e0 + ce * 8 + j];

#pragma unroll
    for (int i = 0; i < 8; ++i) {
        int tau = tg0 + rt * 8 + i;
        if (tau < tau1) {
            float* yrow = Yw + ((size_t)b * NTW + (tau - tau0)) * D_DIM + e0 + ce * 8;
#pragma unroll
            for (int j = 0; j < 8; ++j)
                yrow[j] = __fadd_rn(acc[i][j], bias[j]);
        }
    }
}

// ---------------------------------------------------------------------------
// K2: FULLY FUSED depthwise conv + LIF scan + residual add (R12: spike_add
// absorbed — out[t] = fl(s + inp[t]) stored directly; sw bitmasks gone).
// t-chunked, 64-step f32 warmup (chunk 0 exact; warm & true trajectories
// share every f32 op and merge bit-exactly at the first agreed spike).
// x (=inp) is prefetched one group ahead in xq0/xq1, mirroring the y-window
// pf0/pf1 parity, so its HBM latency hides under the ~1000-cyc conv group.
// Conv: strict k-ascending mul/add over the same Y bits -> z bit-identical.
// ---------------------------------------------------------------------------
__global__ __launch_bounds__(64, 2)
void dwlif(const float* __restrict__ Yw, const float* __restrict__ w_dw,
           const float* __restrict__ inp, float* __restrict__ out,
           int t0p, int tau0, int NTW)
{
#pragma clang fp contract(off)
    const int lane  = threadIdx.x;
    const int d     = blockIdx.x * 64 + lane;    // 0..511
    const int chunk = blockIdx.y;                // chunk within pass
    const int b     = blockIdx.z;                // 0..15

    const int cstart = t0p + 128 * chunk;
    int ts = cstart - 64; if (ts < 0) ts = 0;    // warmup start (chunk0: 0)
    const int ngroups = (cstart == 0) ? 16 : 24; // (cstart+128 - ts) / 8
    const int outg    = ngroups - 16;            // first output group (even)

    float wd[K_W];
#pragma unroll
    for (int k = 0; k < K_W; ++k) wd[k] = w_dw[d * K_W + k];

    const float* __restrict__ ybase = Yw  + (size_t)b * NTW * D_DIM + d;
    const float* __restrict__ xbase = inp + (size_t)b * D_DIM + d;
    float*       __restrict__ obase = out + (size_t)b * D_DIM + d;

    auto YLD = [&](int tau) -> float {
        int idx = tau - tau0;
        idx = idx < 0 ? 0 : idx;
        idx = idx >= NTW ? NTW - 1 : idx;        // clamped addr, always valid
        float ld = ybase[(size_t)idx * D_DIM];
        return (tau >= 0 && tau < T_DIM) ? ld : 0.0f;   // zero-pad select
    };

    // window: yw[i] = y[tg - 15 + i] for current group base tg (i in [0,54))
    float yw[54], pf0[8], pf1[8], xq0[8], xq1[8];
#pragma unroll
    for (int i = 0; i < 54; ++i) yw[i] = YLD(ts - PAD + i);
#pragma unroll
    for (int j = 0; j < 8; ++j) pf0[j] = YLD(ts + 39 + j);
    if (outg == 0) {                             // chunk 0: group 0 emits
#pragma unroll
        for (int j = 0; j < 8; ++j) xq0[j] = xbase[(size_t)(ts + j) * ST];
    }

    float v = 0.0f;

#define GROUP(G_EXPR, PF_IN, PF_OUT, XQ_IN, XQ_OUT)                          \
    {                                                                        \
        const int g  = (G_EXPR);                                             \
        const int tg = ts + 8 * g;                                           \
        _Pragma("unroll")                                                    \
        for (int j = 0; j < 8; ++j) PF_OUT[j] = YLD(tg + 47 + j);            \
        if (g + 1 >= outg) {                     /* x for group g+1 */       \
            _Pragma("unroll")                                                \
            for (int j = 0; j < 8; ++j) {                                    \
                int tx = tg + 8 + j;                                         \
                tx = (tx > T_DIM - 1) ? T_DIM - 1 : tx;   /* tail clamp */   \
                XQ_OUT[j] = xbase[(size_t)tx * ST];                          \
            }                                                                \
        }                                                                    \
        _Pragma("unroll")                                                    \
        for (int s = 0; s < 8; ++s) {                                        \
            float z = 0.0f;                                                  \
            _Pragma("unroll")                                                \
            for (int k = 0; k < K_W; ++k)     /* strict ascending k */       \
                z = __fadd_rn(z, __fmul_rn(wd[k], yw[s + k]));               \
            v = __fadd_rn(__fmul_rn(v, 0.5f), z);                            \
            const bool sp = (v >= 1.0f);                                     \
            if (g >= outg)                                                   \
                obase[(size_t)(tg + s) * ST] =                               \
                    __fadd_rn(sp ? 1.0f : 0.0f, XQ_IN[s]);                   \
            v = sp ? 0.0f : v;                /* hard reset (detach) */      \
        }                                                                    \
        _Pragma("unroll")                                                    \
        for (int i = 0; i < 46; ++i) yw[i] = yw[i + 8];                      \
        _Pragma("unroll")                                                    \
        for (int j = 0; j < 8; ++j) yw[46 + j] = PF_IN[j];                   \
    }

    for (int it = 0; it < ngroups; it += 2) {
        GROUP(it,     pf0, pf1, xq0, xq1);
        GROUP(it + 1, pf1, pf0, xq1, xq0);
    }
#undef GROUP
}

// ---------------------------------------------------------------------------
// Driver: 2 kernels per pass. ws = Yw only (NTW rows of 32KB). L from
// ws_size (launch-time constant; R9/R11 rocprof confirmed L=1024 here).
// Pass tau window reaches t0-79 for the first chunk's warmup taps.
// ---------------------------------------------------------------------------
extern "C" void kernel_launch(void* const* d_in, const int* in_sizes, int n_in,
                              void* d_out, int out_size, void* d_ws, size_t ws_size,
                              hipStream_t stream)
{
    const float* inp  = (const float*)d_in[0];   // (T,B,D)
    const float* w_pw = (const float*)d_in[1];   // (D,D)
    const float* b_pw = (const float*)d_in[2];   // (D)
    const float* w_dw = (const float*)d_in[3];   // (D,K)
    float* out = (float*)d_out;

    auto need = [](int L) -> size_t {
        int ntw = (L + 94 > T_DIM) ? T_DIM : (L + 94);
        return (size_t)ntw * (ST * sizeof(float));
    };
    int L = 128;
    if      (ws_size >= need(1024)) L = 1024;
    else if (ws_size >= need(512))  L = 512;
    else if (ws_size >= need(256))  L = 256;

    const int NTWmax = (L + 94 > T_DIM) ? T_DIM : (L + 94);
    float* Yw = (float*)d_ws;
    (void)NTWmax;

    const int P = T_DIM / L;
    for (int p = 0; p < P; ++p) {
        const int t0   = p * L;
        const int t1   = t0 + L;
        const int tau0 = (t0 - 79 > 0) ? (t0 - 79) : 0;      // warmup halo
        const int tau1 = (t1 + PAD < T_DIM) ? (t1 + PAD) : T_DIM;
        const int NTW  = tau1 - tau0;

        dim3 g1(D_DIM / 128, (NTW + 127) / 128, B_DIM);
        pw_gemm<<<g1, 256, 0, stream>>>(inp, w_pw, b_pw, Yw, tau0, tau1, NTW);

        dim3 g2(D_DIM / 64, L / 128, B_DIM);
        dwlif<<<g2, 64, 0, stream>>>(Yw, w_dw, inp, out, t0, tau0, NTW);
    }
}